// Round 3
// baseline (221.036 us; speedup 1.0000x reference)
//
#include <hip/hip_runtime.h>
#include <math.h>

// Problem constants: B=8, C=256, CR=32, N=4096 (=64*64)
#define B_ 8
#define C_ 256
#define CR_ 32
#define N_ 4096
#define NH_ 8  // KV split factor: 4096 single-wave blocks = 4 waves/SIMD

typedef __attribute__((ext_vector_type(8))) short bf16x8;   // MFMA A/B frag
typedef __attribute__((ext_vector_type(4))) short bf16x4;
typedef __attribute__((ext_vector_type(4))) float f32x4;    // 16x16 C/D frag
typedef __attribute__((ext_vector_type(16))) float f32x16;  // 32x32 C/D frag
typedef __attribute__((ext_vector_type(2))) unsigned uint32x2;

#if defined(__has_builtin)
#if __has_builtin(__builtin_amdgcn_permlane32_swap)
#define HAVE_PLSWAP 1
#endif
#endif

__device__ inline short f2bf(float f) {  // RTNE
  union { float f; unsigned u; } v; v.f = f;
  unsigned r = v.u + 0x7FFFu + ((v.u >> 16) & 1u);
  return (short)(r >> 16);
}
__device__ inline float bf2f(short h) {
  union { unsigned u; float f; } v; v.u = ((unsigned)(unsigned short)h) << 16;
  return v.f;
}
__device__ inline short f2bf_r(float f) {  // cheap round for hot paths
  return (short)((__float_as_uint(f) + 0x8000u) >> 16);
}

// ---------------------------------------------------------------------------
// Kernel 0: weight prep.  WtHi/WtLo = split-bf16 of Wt (log2e folded into Q
// rows 32..63 so softmax runs in exp2 domain).  WoB = bf16(Wo * scale).
// ---------------------------------------------------------------------------
__global__ __launch_bounds__(256) void prep_weights(const float* __restrict__ Wt,
                                                    const float* __restrict__ Wo,
                                                    const float* __restrict__ scale,
                                                    short* __restrict__ WtHi,
                                                    short* __restrict__ WtLo,
                                                    short* __restrict__ WoB) {
  const int blk = blockIdx.x, tid = threadIdx.x;
  if (blk < 96) {
    float v = Wt[blk * C_ + tid];
    if (blk >= 32 && blk < 64) v *= 1.44269504f;  // log2(e) into Q
    const short h = f2bf(v);
    WtHi[blk * C_ + tid] = h;
    WtLo[blk * C_ + tid] = f2bf(v - bf2f(h));
  } else {
    const int idx = (blk - 96) * 256 + tid;
    WoB[idx] = f2bf(Wo[idx] * scale[0]);
  }
}

// ---------------------------------------------------------------------------
// Kernel 1: QKV projection, pure MFMA, no LDS, x prefetched one chunk ahead.
//   t_tr[b][n][0..31]=K, [32..63]=Q*log2e (bf16);  Vg[b][c][n]=V (bf16)
// ---------------------------------------------------------------------------
__global__ __launch_bounds__(256) void qkv_mfma(const float* __restrict__ x,
                                                const short* __restrict__ WtHi,
                                                const short* __restrict__ WtLo,
                                                short* __restrict__ t_tr,
                                                short* __restrict__ Vg) {
  const int b = blockIdx.y;
  const int tid = threadIdx.x;
  const int wave = tid >> 6, lane = tid & 63;
  const int col = lane & 15, quad = lane >> 4;
  const int n0 = (blockIdx.x * 4 + wave) * 16;

  const f32x4 z4 = {0.f, 0.f, 0.f, 0.f};
  f32x4 acc[6] = {z4, z4, z4, z4, z4, z4};  // 0..3 = KQ o-tiles, 4..5 = V

  const float* xb = x + (size_t)b * C_ * N_ + n0 + col;
  float xcur[8], xnxt[8];
#pragma unroll
  for (int j = 0; j < 8; ++j) xcur[j] = xb[(size_t)(quad * 8 + j) * N_];

#pragma unroll 2
  for (int c0 = 0; c0 < C_; c0 += 32) {
    if (c0 < C_ - 32) {
#pragma unroll
      for (int j = 0; j < 8; ++j)
        xnxt[j] = xb[(size_t)(c0 + 32 + quad * 8 + j) * N_];
    }
    bf16x8 xh, xl;
#pragma unroll
    for (int j = 0; j < 8; ++j) {
      const short h = (short)(__float_as_uint(xcur[j]) >> 16);  // trunc hi
      xh[j] = h;
      xl[j] = f2bf_r(xcur[j] - bf2f(h));
    }
#pragma unroll
    for (int ot = 0; ot < 4; ++ot) {  // K/Q: B-operand = Wt rows 0..63
      const int off = (ot * 16 + col) * C_ + c0 + quad * 8;
      const bf16x8 bh = *(const bf16x8*)(WtHi + off);
      const bf16x8 bl = *(const bf16x8*)(WtLo + off);
      acc[ot] = __builtin_amdgcn_mfma_f32_16x16x32_bf16(xh, bh, acc[ot], 0, 0, 0);
      acc[ot] = __builtin_amdgcn_mfma_f32_16x16x32_bf16(xl, bh, acc[ot], 0, 0, 0);
      acc[ot] = __builtin_amdgcn_mfma_f32_16x16x32_bf16(xh, bl, acc[ot], 0, 0, 0);
    }
#pragma unroll
    for (int ct = 0; ct < 2; ++ct) {  // V: A-operand = Wt rows 64..95
      const int off = ((64 + ct * 16) + col) * C_ + c0 + quad * 8;
      const bf16x8 ah = *(const bf16x8*)(WtHi + off);
      const bf16x8 al = *(const bf16x8*)(WtLo + off);
      acc[4 + ct] = __builtin_amdgcn_mfma_f32_16x16x32_bf16(ah, xh, acc[4 + ct], 0, 0, 0);
      acc[4 + ct] = __builtin_amdgcn_mfma_f32_16x16x32_bf16(ah, xl, acc[4 + ct], 0, 0, 0);
      acc[4 + ct] = __builtin_amdgcn_mfma_f32_16x16x32_bf16(al, xh, acc[4 + ct], 0, 0, 0);
    }
#pragma unroll
    for (int j = 0; j < 8; ++j) xcur[j] = xnxt[j];
  }
  // K/Q epilogue: D[n][o]
#pragma unroll
  for (int ot = 0; ot < 4; ++ot)
#pragma unroll
    for (int r = 0; r < 4; ++r)
      t_tr[((size_t)b * N_ + n0 + quad * 4 + r) * 64 + ot * 16 + col] =
          f2bf(acc[ot][r]);
  // V epilogue: D[c][n]
#pragma unroll
  for (int ct = 0; ct < 2; ++ct)
#pragma unroll
    for (int r = 0; r < 4; ++r)
      Vg[(size_t)b * CR_ * N_ + (size_t)(ct * 16 + quad * 4 + r) * N_ + n0 + col] =
          f2bf(acc[4 + ct][r]);
}

// ---------------------------------------------------------------------------
// Kernel 2: 32x32-MFMA flash attention, zero LDS, in-register P transform.
// Wave = 64 query cols (2 j-tiles of 32) x one KV-EIGHTH (512 keys in 8
// tiles of 64).  Grid (64 jb, 8 eighths, 8 b) = 4096 single-wave blocks
// = exactly 4 waves/SIMD IF the register class allows it.
// Round-2 post-mortem: explicit K/V next-iter prefetch (kfn/vfn, 32 regs)
// pushed arch VGPR to 108 (+32 acc = 140 unified > 128) -> stuck in the
// 2-waves/SIMD class, occupancy 17%, latency-bound (VALUBusy 39, Mfma 14).
// Fix: drop the manual double-buffer (at 4 waves/SIMD, TLP + the second
// it-tile's loads overlapping the first's ~600-cyc compute hide L2 latency),
// load K/V per it-tile (16 live regs), pin __launch_bounds__(64,4)
// (128-unified budget, now satisfiable: ~72 arch + 32 acc), and
// #pragma unroll 1 on the iter loop so the unroller can't re-inflate
// pressure.  Tripwire: if WRITE_SIZE >> 17.4 MB, the cap caused spills.
// S = K^T Q via 32x32x16; P transform via v_permlane32_swap (VALU
// cross-lane); l = sum p via VALU tree; partials (bf16 O, f32 l) -> global.
// ---------------------------------------------------------------------------
__global__ __launch_bounds__(64, 4) void flash_attn(const short* __restrict__ t_tr,
                                                    const short* __restrict__ Vg,
                                                    short* __restrict__ OPart,
                                                    float* __restrict__ LPart) {
  const int b = blockIdx.z, hq = blockIdx.y;  // hq = KV eighth, 0..7
  const int j0 = blockIdx.x * 64;
  const int lane = threadIdx.x;
  const int j32 = lane & 31, h32 = lane >> 5;
  const short* T = t_tr + (size_t)b * N_ * 64;
  const short* V = Vg + (size_t)b * CR_ * N_;

  const f32x16 z16 = {0.f};
  // Q B-frags, loop-invariant: qf[jt][chunk]
  bf16x8 qf[2][2];
#pragma unroll
  for (int jt = 0; jt < 2; ++jt)
#pragma unroll
    for (int ch = 0; ch < 2; ++ch)
      qf[jt][ch] = *(const bf16x8*)(T + (size_t)(j0 + jt * 32 + j32) * 64 + 32 +
                                    ch * 16 + h32 * 8);

  f32x16 acc[2] = {z16, z16};
  float ps[2] = {0.f, 0.f};

  const int ibase = hq * 512;

#pragma unroll 1
  for (int iter = 0; iter < 8; ++iter) {
    const int i0 = ibase + iter * 64;
#pragma unroll
    for (int it = 0; it < 2; ++it) {
      const int ioff = i0 + it * 32;
      // K frags for this 32-key tile (A-operand of S): rows ioff..ioff+31
      const short* Trow = T + (size_t)(ioff + j32) * 64 + h32 * 8;
      const bf16x8 ka = *(const bf16x8*)(Trow);        // k-chunk 0 (c 0..15)
      const bf16x8 kb = *(const bf16x8*)(Trow + 16);   // k-chunk 1 (c 16..31)
      // V frags for this tile (A-operand of PV): V[c=j32][keys ioff..+31]
      const short* Vrow = V + (size_t)j32 * N_ + ioff + h32 * 8;
      const bf16x8 va = *(const bf16x8*)(Vrow);        // keys ioff..+15
      const bf16x8 vb = *(const bf16x8*)(Vrow + 16);   // keys +16..+31
#pragma unroll
      for (int jt = 0; jt < 2; ++jt) {
        // ---- S tile (32 i x 32 j), k=32 over two chunks ----
        __builtin_amdgcn_s_setprio(1);
        f32x16 s = __builtin_amdgcn_mfma_f32_32x32x16_bf16(ka, qf[jt][0], z16, 0, 0, 0);
        s = __builtin_amdgcn_mfma_f32_32x32x16_bf16(kb, qf[jt][1], s, 0, 0, 0);
        __builtin_amdgcn_s_setprio(0);
        // ---- p = exp2(s); l tree; pack row-pairs into dwords ----
        float p[16];
#pragma unroll
        for (int r = 0; r < 16; ++r) p[r] = __builtin_amdgcn_exp2f(s[r]);
        ps[jt] += (((p[0] + p[1]) + (p[2] + p[3])) + ((p[4] + p[5]) + (p[6] + p[7]))) +
                  (((p[8] + p[9]) + (p[10] + p[11])) + ((p[12] + p[13]) + (p[14] + p[15])));
        unsigned d[8];
#pragma unroll
        for (int k = 0; k < 8; ++k) {
          const unsigned u0 = __float_as_uint(p[2 * k]) + 0x8000u;
          const unsigned u1 = __float_as_uint(p[2 * k + 1]) + 0x8000u;
          d[k] = __builtin_amdgcn_perm(u1, u0, 0x07060302u);  // (bf16 odd)<<16 | bf16 even
        }
        // ---- B-frags for PV: rows [8*h32, 8*h32+8) of each 16-row chunk ----
        union { unsigned u[4]; bf16x8 v; } f0, f1;
#ifdef HAVE_PLSWAP
        {
          const uint32x2 r0 = __builtin_amdgcn_permlane32_swap(d[0], d[2], false, false);
          f0.u[0] = r0[0]; f0.u[2] = r0[1];
          const uint32x2 r1 = __builtin_amdgcn_permlane32_swap(d[1], d[3], false, false);
          f0.u[1] = r1[0]; f0.u[3] = r1[1];
          const uint32x2 r2 = __builtin_amdgcn_permlane32_swap(d[4], d[6], false, false);
          f1.u[0] = r2[0]; f1.u[2] = r2[1];
          const uint32x2 r3 = __builtin_amdgcn_permlane32_swap(d[5], d[7], false, false);
          f1.u[1] = r3[0]; f1.u[3] = r3[1];
        }
#else
        {
          unsigned xw[8];
#pragma unroll
          for (int k = 0; k < 8; ++k) xw[k] = __shfl_xor((int)d[k], 32);
          f0.u[0] = h32 ? xw[2] : d[0];
          f0.u[1] = h32 ? xw[3] : d[1];
          f0.u[2] = h32 ? d[2] : xw[0];
          f0.u[3] = h32 ? d[3] : xw[1];
          f1.u[0] = h32 ? xw[6] : d[4];
          f1.u[1] = h32 ? xw[7] : d[5];
          f1.u[2] = h32 ? d[6] : xw[4];
          f1.u[3] = h32 ? d[7] : xw[5];
        }
#endif
        // ---- O += V @ P ----
        __builtin_amdgcn_s_setprio(1);
        acc[jt] = __builtin_amdgcn_mfma_f32_32x32x16_bf16(va, f0.v, acc[jt], 0, 0, 0);
        acc[jt] = __builtin_amdgcn_mfma_f32_32x32x16_bf16(vb, f1.v, acc[jt], 0, 0, 0);
        __builtin_amdgcn_s_setprio(0);
      }
    }
  }

  // ---- epilogue: finish l across halves, write O/l partials ----
  const size_t base = ((size_t)b * NH_ + hq) * N_;
#pragma unroll
  for (int jt = 0; jt < 2; ++jt) {
    const float l = ps[jt] + __shfl_xor(ps[jt], 32);
    const int jg = j0 + jt * 32 + j32;
    if (h32 == 0) LPart[base + jg] = l;
    short* OP = OPart + (base + jg) * 32;
#pragma unroll
    for (int g = 0; g < 4; ++g) {  // regs 4g..4g+3 -> c = 8g + 4*h32 + 0..3
      bf16x4 o = {f2bf(acc[jt][4 * g + 0]), f2bf(acc[jt][4 * g + 1]),
                  f2bf(acc[jt][4 * g + 2]), f2bf(acc[jt][4 * g + 3])};
      *(bf16x4*)(OP + 8 * g + 4 * h32) = o;
    }
  }
}

// ---------------------------------------------------------------------------
// Kernel 3: merge 8 KV-eighth partials, normalize, out-proj, residual.
// Grid (64 n-blocks, 2 co-halves, 8 b) = 1024 blocks.
// out[b,co,n] = WoB @ (sum_h O_h / sum_h l_h) + x
// ---------------------------------------------------------------------------
__global__ __launch_bounds__(256) void out_proj(const short* __restrict__ OPart,
                                                const float* __restrict__ LPart,
                                                const short* __restrict__ WoB,
                                                const float* __restrict__ x,
                                                float* __restrict__ out) {
  const int b = blockIdx.z, chalf = blockIdx.y;
  const int tid = threadIdx.x;
  const int wave = tid >> 6, lane = tid & 63;
  const int col = lane & 15, quad = lane >> 4;
  const int jg = blockIdx.x * 64 + wave * 16 + col;  // global n/j
  const int n0 = blockIdx.x * 64 + wave * 16;

  float osum[8];
#pragma unroll
  for (int e = 0; e < 8; ++e) osum[e] = 0.f;
  float lsum = 0.f;
#pragma unroll
  for (int h = 0; h < NH_; ++h) {
    const size_t p = ((size_t)b * NH_ + h) * N_ + jg;
    const bf16x8 o = *(const bf16x8*)(OPart + p * 32 + quad * 8);
#pragma unroll
    for (int e = 0; e < 8; ++e) osum[e] += bf2f(o[e]);
    lsum += LPart[p];
  }
  const float linv = 1.f / lsum;
  bf16x8 bf;
#pragma unroll
  for (int e = 0; e < 8; ++e) bf[e] = f2bf(osum[e] * linv);

  const f32x4 z4 = {0.f, 0.f, 0.f, 0.f};
  const float* xb = x + (size_t)b * C_ * N_;
  float* ob = out + (size_t)b * C_ * N_;
#pragma unroll
  for (int ct = 0; ct < 8; ++ct) {
    const int ctg = chalf * 8 + ct;
    const bf16x8 af = *(const bf16x8*)(WoB + (ctg * 16 + col) * 32 + quad * 8);
    const f32x4 a = __builtin_amdgcn_mfma_f32_16x16x32_bf16(af, bf, z4, 0, 0, 0);
#pragma unroll
    for (int r = 0; r < 4; ++r) {
      const size_t idx = (size_t)(ctg * 16 + quad * 4 + r) * N_ + n0 + col;
      ob[idx] = a[r] + xb[idx];
    }
  }
}

// ---------------------------------------------------------------------------
extern "C" void kernel_launch(void* const* d_in, const int* in_sizes, int n_in,
                              void* d_out, int out_size, void* d_ws,
                              size_t ws_size, hipStream_t stream) {
  const float* x = (const float*)d_in[0];      // [8,256,64,64]
  const float* Wt = (const float*)d_in[1];     // [96,256]
  const float* Wo = (const float*)d_in[2];     // [256,32]
  const float* scale = (const float*)d_in[3];  // [1]
  float* out = (float*)d_out;

  // ws: OPart bf16 [8][8][4096][32] (16.8 MB) | LPart f32 [8][8][4096] (1.0 MB)
  //   | t_tr bf16 (4.2 MB) | Vg bf16 (2.1 MB) | WtHi | WtLo | WoB  (~24.5 MB)
  short* OPart = (short*)d_ws;
  float* LPart = (float*)(OPart + (size_t)B_ * NH_ * N_ * 32);
  short* t_tr = (short*)(LPart + (size_t)B_ * NH_ * N_);
  short* Vg = t_tr + (size_t)B_ * N_ * 64;
  short* WtHi = Vg + (size_t)B_ * CR_ * N_;
  short* WtLo = WtHi + 96 * C_;
  short* WoB = WtLo + 96 * C_;

  prep_weights<<<dim3(128), 256, 0, stream>>>(Wt, Wo, scale, WtHi, WtLo, WoB);
  qkv_mfma<<<dim3(64, B_), 256, 0, stream>>>(x, WtHi, WtLo, t_tr, Vg);
  flash_attn<<<dim3(64, NH_, B_), 64, 0, stream>>>(t_tr, Vg, OPart, LPart);
  out_proj<<<dim3(64, 2, B_), 256, 0, stream>>>(OPart, LPart, WoB, x, out);
}

// Round 4
// 183.589 us; speedup vs baseline: 1.2040x; 1.2040x over previous
//
#include <hip/hip_runtime.h>
#include <math.h>

// Problem constants: B=8, C=256, CR=32, N=4096 (=64*64)
#define B_ 8
#define C_ 256
#define CR_ 32
#define N_ 4096
#define NH_ 4  // KV split factor (quarters)

typedef __attribute__((ext_vector_type(8))) short bf16x8;   // MFMA A/B frag
typedef __attribute__((ext_vector_type(4))) short bf16x4;
typedef __attribute__((ext_vector_type(4))) float f32x4;    // 16x16 C/D frag
typedef __attribute__((ext_vector_type(16))) float f32x16;  // 32x32 C/D frag
typedef __attribute__((ext_vector_type(2))) unsigned uint32x2;

#if defined(__has_builtin)
#if __has_builtin(__builtin_amdgcn_permlane32_swap)
#define HAVE_PLSWAP 1
#endif
#endif

__device__ inline short f2bf(float f) {  // RTNE
  union { float f; unsigned u; } v; v.f = f;
  unsigned r = v.u + 0x7FFFu + ((v.u >> 16) & 1u);
  return (short)(r >> 16);
}
__device__ inline float bf2f(short h) {
  union { unsigned u; float f; } v; v.u = ((unsigned)(unsigned short)h) << 16;
  return v.f;
}
__device__ inline short f2bf_r(float f) {  // cheap round for hot paths
  return (short)((__float_as_uint(f) + 0x8000u) >> 16);
}

// ---------------------------------------------------------------------------
// Kernel 0: weight prep.  WtHi/WtLo = split-bf16 of Wt (log2e folded into Q
// rows 32..63 so softmax runs in exp2 domain).  WoB = bf16(Wo * scale).
// ---------------------------------------------------------------------------
__global__ __launch_bounds__(256) void prep_weights(const float* __restrict__ Wt,
                                                    const float* __restrict__ Wo,
                                                    const float* __restrict__ scale,
                                                    short* __restrict__ WtHi,
                                                    short* __restrict__ WtLo,
                                                    short* __restrict__ WoB) {
  const int blk = blockIdx.x, tid = threadIdx.x;
  if (blk < 96) {
    float v = Wt[blk * C_ + tid];
    if (blk >= 32 && blk < 64) v *= 1.44269504f;  // log2(e) into Q
    const short h = f2bf(v);
    WtHi[blk * C_ + tid] = h;
    WtLo[blk * C_ + tid] = f2bf(v - bf2f(h));
  } else {
    const int idx = (blk - 96) * 256 + tid;
    WoB[idx] = f2bf(Wo[idx] * scale[0]);
  }
}

// ---------------------------------------------------------------------------
// Kernel 1: QKV projection, pure MFMA, no LDS, x prefetched one chunk ahead.
//   t_tr[b][n][0..31]=K, [32..63]=Q*log2e (bf16);  Vg[b][c][n]=V (bf16)
// ---------------------------------------------------------------------------
__global__ __launch_bounds__(256) void qkv_mfma(const float* __restrict__ x,
                                                const short* __restrict__ WtHi,
                                                const short* __restrict__ WtLo,
                                                short* __restrict__ t_tr,
                                                short* __restrict__ Vg) {
  const int b = blockIdx.y;
  const int tid = threadIdx.x;
  const int wave = tid >> 6, lane = tid & 63;
  const int col = lane & 15, quad = lane >> 4;
  const int n0 = (blockIdx.x * 4 + wave) * 16;

  const f32x4 z4 = {0.f, 0.f, 0.f, 0.f};
  f32x4 acc[6] = {z4, z4, z4, z4, z4, z4};  // 0..3 = KQ o-tiles, 4..5 = V

  const float* xb = x + (size_t)b * C_ * N_ + n0 + col;
  float xcur[8], xnxt[8];
#pragma unroll
  for (int j = 0; j < 8; ++j) xcur[j] = xb[(size_t)(quad * 8 + j) * N_];

#pragma unroll 2
  for (int c0 = 0; c0 < C_; c0 += 32) {
    if (c0 < C_ - 32) {
#pragma unroll
      for (int j = 0; j < 8; ++j)
        xnxt[j] = xb[(size_t)(c0 + 32 + quad * 8 + j) * N_];
    }
    bf16x8 xh, xl;
#pragma unroll
    for (int j = 0; j < 8; ++j) {
      const short h = (short)(__float_as_uint(xcur[j]) >> 16);  // trunc hi
      xh[j] = h;
      xl[j] = f2bf_r(xcur[j] - bf2f(h));
    }
#pragma unroll
    for (int ot = 0; ot < 4; ++ot) {  // K/Q: B-operand = Wt rows 0..63
      const int off = (ot * 16 + col) * C_ + c0 + quad * 8;
      const bf16x8 bh = *(const bf16x8*)(WtHi + off);
      const bf16x8 bl = *(const bf16x8*)(WtLo + off);
      acc[ot] = __builtin_amdgcn_mfma_f32_16x16x32_bf16(xh, bh, acc[ot], 0, 0, 0);
      acc[ot] = __builtin_amdgcn_mfma_f32_16x16x32_bf16(xl, bh, acc[ot], 0, 0, 0);
      acc[ot] = __builtin_amdgcn_mfma_f32_16x16x32_bf16(xh, bl, acc[ot], 0, 0, 0);
    }
#pragma unroll
    for (int ct = 0; ct < 2; ++ct) {  // V: A-operand = Wt rows 64..95
      const int off = ((64 + ct * 16) + col) * C_ + c0 + quad * 8;
      const bf16x8 ah = *(const bf16x8*)(WtHi + off);
      const bf16x8 al = *(const bf16x8*)(WtLo + off);
      acc[4 + ct] = __builtin_amdgcn_mfma_f32_16x16x32_bf16(ah, xh, acc[4 + ct], 0, 0, 0);
      acc[4 + ct] = __builtin_amdgcn_mfma_f32_16x16x32_bf16(ah, xl, acc[4 + ct], 0, 0, 0);
      acc[4 + ct] = __builtin_amdgcn_mfma_f32_16x16x32_bf16(al, xh, acc[4 + ct], 0, 0, 0);
    }
#pragma unroll
    for (int j = 0; j < 8; ++j) xcur[j] = xnxt[j];
  }
  // K/Q epilogue: D[n][o]
#pragma unroll
  for (int ot = 0; ot < 4; ++ot)
#pragma unroll
    for (int r = 0; r < 4; ++r)
      t_tr[((size_t)b * N_ + n0 + quad * 4 + r) * 64 + ot * 16 + col] =
          f2bf(acc[ot][r]);
  // V epilogue: D[c][n]
#pragma unroll
  for (int ct = 0; ct < 2; ++ct)
#pragma unroll
    for (int r = 0; r < 4; ++r)
      Vg[(size_t)b * CR_ * N_ + (size_t)(ct * 16 + quad * 4 + r) * N_ + n0 + col] =
          f2bf(acc[4 + ct][r]);
}

// ---------------------------------------------------------------------------
// Kernel 2: 32x32-MFMA flash attention, zero LDS, in-register P transform.
// ROUND-4 RESTRUCTURE: wave = ONE 32-col j-tile (was two) x one KV-quarter
// (1024 keys, 16 iters of 64).  Halves per-wave state: acc 32->16 regs,
// qf 16->8, p/d live ranges halved.  Demand ~90-105 unified, which FITS the
// 128-unified budget of the 4-waves/SIMD class -> __launch_bounds__(64,4)
// is now satisfiable without spill (rounds 1/3 spilled because demand was
// ~140 with 2 j-tiles; round 2 unbound landed 108 arch + 32 acc = 2/SIMD).
// Grid (128 jb, 4 quarters, 8 b) = 4096 single-wave blocks = 4 waves/SIMD.
// K/V frags are re-read once more per j-tile vs the 2-jt version, but
// t_tr+Vg (6.3 MB) are L2-resident -> FETCH stays small.
// Tripwire: WRITE_SIZE must stay ~8.7 MB (OPart+LPart); growth = spill.
// S = K^T Q via 32x32x16; P transform via v_permlane32_swap (VALU
// cross-lane); l = sum p via VALU tree; partials (bf16 O, f32 l) -> global.
// ---------------------------------------------------------------------------
__global__ __launch_bounds__(64, 4) void flash_attn(const short* __restrict__ t_tr,
                                                    const short* __restrict__ Vg,
                                                    short* __restrict__ OPart,
                                                    float* __restrict__ LPart) {
  const int b = blockIdx.z, hq = blockIdx.y;  // hq = KV quarter, 0..3
  const int j0 = blockIdx.x * 32;             // 32-col j-tile
  const int lane = threadIdx.x;
  const int j32 = lane & 31, h32 = lane >> 5;
  const short* T = t_tr + (size_t)b * N_ * 64;
  const short* V = Vg + (size_t)b * CR_ * N_;

  const f32x16 z16 = {0.f};
  // Q B-frags, loop-invariant: two k-chunks of the single j-tile
  const short* Qrow = T + (size_t)(j0 + j32) * 64 + 32 + h32 * 8;
  const bf16x8 qf0 = *(const bf16x8*)(Qrow);
  const bf16x8 qf1 = *(const bf16x8*)(Qrow + 16);

  f32x16 acc = z16;
  float ps = 0.f;

  const int ibase = hq * 1024;

#pragma unroll 1
  for (int iter = 0; iter < 16; ++iter) {
    const int i0 = ibase + iter * 64;
#pragma unroll
    for (int it = 0; it < 2; ++it) {
      const int ioff = i0 + it * 32;
      // K frags for this 32-key tile (A-operand of S): rows ioff..ioff+31
      const short* Trow = T + (size_t)(ioff + j32) * 64 + h32 * 8;
      const bf16x8 ka = *(const bf16x8*)(Trow);        // k-chunk 0 (c 0..15)
      const bf16x8 kb = *(const bf16x8*)(Trow + 16);   // k-chunk 1 (c 16..31)
      // V frags for this tile (A-operand of PV): V[c=j32][keys ioff..+31]
      const short* Vrow = V + (size_t)j32 * N_ + ioff + h32 * 8;
      const bf16x8 va = *(const bf16x8*)(Vrow);        // keys ioff..+15
      const bf16x8 vb = *(const bf16x8*)(Vrow + 16);   // keys +16..+31
      // ---- S tile (32 i x 32 j), k=32 over two chunks ----
      __builtin_amdgcn_s_setprio(1);
      f32x16 s = __builtin_amdgcn_mfma_f32_32x32x16_bf16(ka, qf0, z16, 0, 0, 0);
      s = __builtin_amdgcn_mfma_f32_32x32x16_bf16(kb, qf1, s, 0, 0, 0);
      __builtin_amdgcn_s_setprio(0);
      // ---- p = exp2(s); l tree; pack row-pairs into dwords ----
      float p[16];
#pragma unroll
      for (int r = 0; r < 16; ++r) p[r] = __builtin_amdgcn_exp2f(s[r]);
      ps += (((p[0] + p[1]) + (p[2] + p[3])) + ((p[4] + p[5]) + (p[6] + p[7]))) +
            (((p[8] + p[9]) + (p[10] + p[11])) + ((p[12] + p[13]) + (p[14] + p[15])));
      unsigned d[8];
#pragma unroll
      for (int k = 0; k < 8; ++k) {
        const unsigned u0 = __float_as_uint(p[2 * k]) + 0x8000u;
        const unsigned u1 = __float_as_uint(p[2 * k + 1]) + 0x8000u;
        d[k] = __builtin_amdgcn_perm(u1, u0, 0x07060302u);  // (bf16 odd)<<16 | bf16 even
      }
      // ---- B-frags for PV: rows [8*h32, 8*h32+8) of each 16-row chunk ----
      union { unsigned u[4]; bf16x8 v; } f0, f1;
#ifdef HAVE_PLSWAP
      {
        const uint32x2 r0 = __builtin_amdgcn_permlane32_swap(d[0], d[2], false, false);
        f0.u[0] = r0[0]; f0.u[2] = r0[1];
        const uint32x2 r1 = __builtin_amdgcn_permlane32_swap(d[1], d[3], false, false);
        f0.u[1] = r1[0]; f0.u[3] = r1[1];
        const uint32x2 r2 = __builtin_amdgcn_permlane32_swap(d[4], d[6], false, false);
        f1.u[0] = r2[0]; f1.u[2] = r2[1];
        const uint32x2 r3 = __builtin_amdgcn_permlane32_swap(d[5], d[7], false, false);
        f1.u[1] = r3[0]; f1.u[3] = r3[1];
      }
#else
      {
        unsigned xw[8];
#pragma unroll
        for (int k = 0; k < 8; ++k) xw[k] = __shfl_xor((int)d[k], 32);
        f0.u[0] = h32 ? xw[2] : d[0];
        f0.u[1] = h32 ? xw[3] : d[1];
        f0.u[2] = h32 ? d[2] : xw[0];
        f0.u[3] = h32 ? d[3] : xw[1];
        f1.u[0] = h32 ? xw[6] : d[4];
        f1.u[1] = h32 ? xw[7] : d[5];
        f1.u[2] = h32 ? d[6] : xw[4];
        f1.u[3] = h32 ? d[7] : xw[5];
      }
#endif
      // ---- O += V @ P ----
      __builtin_amdgcn_s_setprio(1);
      acc = __builtin_amdgcn_mfma_f32_32x32x16_bf16(va, f0.v, acc, 0, 0, 0);
      acc = __builtin_amdgcn_mfma_f32_32x32x16_bf16(vb, f1.v, acc, 0, 0, 0);
      __builtin_amdgcn_s_setprio(0);
    }
  }

  // ---- epilogue: finish l across halves, write O/l partials ----
  const size_t base = ((size_t)b * NH_ + hq) * N_;
  const float l = ps + __shfl_xor(ps, 32);
  const int jg = j0 + j32;
  if (h32 == 0) LPart[base + jg] = l;
  short* OP = OPart + (base + jg) * 32;
#pragma unroll
  for (int g = 0; g < 4; ++g) {  // regs 4g..4g+3 -> c = 8g + 4*h32 + 0..3
    bf16x4 o = {f2bf(acc[4 * g + 0]), f2bf(acc[4 * g + 1]),
                f2bf(acc[4 * g + 2]), f2bf(acc[4 * g + 3])};
    *(bf16x4*)(OP + 8 * g + 4 * h32) = o;
  }
}

// ---------------------------------------------------------------------------
// Kernel 3: merge 4 KV-quarter partials, normalize, out-proj, residual.
// Grid (64 n-blocks, 2 co-halves, 8 b) = 1024 blocks.
// out[b,co,n] = WoB @ (sum_h O_h / sum_h l_h) + x
// ---------------------------------------------------------------------------
__global__ __launch_bounds__(256) void out_proj(const short* __restrict__ OPart,
                                                const float* __restrict__ LPart,
                                                const short* __restrict__ WoB,
                                                const float* __restrict__ x,
                                                float* __restrict__ out) {
  const int b = blockIdx.z, chalf = blockIdx.y;
  const int tid = threadIdx.x;
  const int wave = tid >> 6, lane = tid & 63;
  const int col = lane & 15, quad = lane >> 4;
  const int jg = blockIdx.x * 64 + wave * 16 + col;  // global n/j
  const int n0 = blockIdx.x * 64 + wave * 16;

  float osum[8];
#pragma unroll
  for (int e = 0; e < 8; ++e) osum[e] = 0.f;
  float lsum = 0.f;
#pragma unroll
  for (int h = 0; h < NH_; ++h) {
    const size_t p = ((size_t)b * NH_ + h) * N_ + jg;
    const bf16x8 o = *(const bf16x8*)(OPart + p * 32 + quad * 8);
#pragma unroll
    for (int e = 0; e < 8; ++e) osum[e] += bf2f(o[e]);
    lsum += LPart[p];
  }
  const float linv = 1.f / lsum;
  bf16x8 bf;
#pragma unroll
  for (int e = 0; e < 8; ++e) bf[e] = f2bf(osum[e] * linv);

  const f32x4 z4 = {0.f, 0.f, 0.f, 0.f};
  const float* xb = x + (size_t)b * C_ * N_;
  float* ob = out + (size_t)b * C_ * N_;
#pragma unroll
  for (int ct = 0; ct < 8; ++ct) {
    const int ctg = chalf * 8 + ct;
    const bf16x8 af = *(const bf16x8*)(WoB + (ctg * 16 + col) * 32 + quad * 8);
    const f32x4 a = __builtin_amdgcn_mfma_f32_16x16x32_bf16(af, bf, z4, 0, 0, 0);
#pragma unroll
    for (int r = 0; r < 4; ++r) {
      const size_t idx = (size_t)(ctg * 16 + quad * 4 + r) * N_ + n0 + col;
      ob[idx] = a[r] + xb[idx];
    }
  }
}

// ---------------------------------------------------------------------------
extern "C" void kernel_launch(void* const* d_in, const int* in_sizes, int n_in,
                              void* d_out, int out_size, void* d_ws,
                              size_t ws_size, hipStream_t stream) {
  const float* x = (const float*)d_in[0];      // [8,256,64,64]
  const float* Wt = (const float*)d_in[1];     // [96,256]
  const float* Wo = (const float*)d_in[2];     // [256,32]
  const float* scale = (const float*)d_in[3];  // [1]
  float* out = (float*)d_out;

  // ws: OPart bf16 [8][4][4096][32] (8.4 MB) | LPart f32 [8][4][4096] (0.5 MB)
  //   | t_tr bf16 (4.2 MB) | Vg bf16 (2.1 MB) | WtHi | WtLo | WoB  (~15 MB)
  short* OPart = (short*)d_ws;
  float* LPart = (float*)(OPart + (size_t)B_ * NH_ * N_ * 32);
  short* t_tr = (short*)(LPart + (size_t)B_ * NH_ * N_);
  short* Vg = t_tr + (size_t)B_ * N_ * 64;
  short* WtHi = Vg + (size_t)B_ * CR_ * N_;
  short* WtLo = WtHi + 96 * C_;
  short* WoB = WtLo + 96 * C_;

  prep_weights<<<dim3(128), 256, 0, stream>>>(Wt, Wo, scale, WtHi, WtLo, WoB);
  qkv_mfma<<<dim3(64, B_), 256, 0, stream>>>(x, WtHi, WtLo, t_tr, Vg);
  flash_attn<<<dim3(128, NH_, B_), 64, 0, stream>>>(t_tr, Vg, OPart, LPart);
  out_proj<<<dim3(64, 2, B_), 256, 0, stream>>>(OPart, LPart, WoB, x, out);
}

// Round 5
// 152.262 us; speedup vs baseline: 1.4517x; 1.2057x over previous
//
#include <hip/hip_runtime.h>
#include <math.h>

// Problem constants: B=8, C=256, CR=32, N=4096 (=64*64)
#define B_ 8
#define C_ 256
#define CR_ 32
#define N_ 4096
#define NH_ 4  // KV split factor (quarters)

typedef __attribute__((ext_vector_type(8))) short bf16x8;   // MFMA A/B frag
typedef __attribute__((ext_vector_type(4))) short bf16x4;
typedef __attribute__((ext_vector_type(4))) float f32x4;    // 16x16 C/D frag
typedef __attribute__((ext_vector_type(16))) float f32x16;  // 32x32 C/D frag
typedef __attribute__((ext_vector_type(2))) unsigned uint32x2;

#if defined(__has_builtin)
#if __has_builtin(__builtin_amdgcn_permlane32_swap)
#define HAVE_PLSWAP 1
#endif
#endif

__device__ inline short f2bf(float f) {  // RTNE
  union { float f; unsigned u; } v; v.f = f;
  unsigned r = v.u + 0x7FFFu + ((v.u >> 16) & 1u);
  return (short)(r >> 16);
}
__device__ inline float bf2f(short h) {
  union { unsigned u; float f; } v; v.u = ((unsigned)(unsigned short)h) << 16;
  return v.f;
}
__device__ inline short f2bf_r(float f) {  // cheap round for hot paths
  return (short)((__float_as_uint(f) + 0x8000u) >> 16);
}

// ---------------------------------------------------------------------------
// FRAGMENT-MAJOR LAYOUTS (round-5 restructure).
// Round-4 post-mortem: flash_attn's K/V/Q loads were 64-lane SCATTERS
// (t_tr rows 128B apart, Vg rows 8KB apart -> each dwordx4 touches 32-64
// cache lines; TA/L1 serializes).  Per-SIMD tile cost ROSE with occupancy
// (R0 ~800 cyc/tile @2 waves, R4 ~1300 @4 waves) = shared-resource bound,
// not latency.  Fix: store K/Q/V in MFMA-fragment order so lane l reads
// base + l*16 -> one coalesced 1KB load per fragment.
//   Kf[b][kt=0..127][ch=0..1][lane=0..63][e=0..7]  (A-frag: key=kt*32+(l&31),
//       c = ch*16 + (l>>5)*8 + e)
//   Qf[b][jt=0..127][ch=0..1][lane][e]             (B-frag: col=jt*32+(l&31),
//       c = ch*16 + (l>>5)*8 + e)
//   Vf[b][n16=0..255][lane][e]                     (A-frag: c=(l&31),
//       key = n16*16 + (l>>5)*8 + e)
// ---------------------------------------------------------------------------

// ---------------------------------------------------------------------------
// Kernel 0: weight prep.  WtHi/WtLo = split-bf16 of Wt (log2e folded into Q
// rows 32..63 so softmax runs in exp2 domain).  WoB = bf16(Wo * scale).
// ---------------------------------------------------------------------------
__global__ __launch_bounds__(256) void prep_weights(const float* __restrict__ Wt,
                                                    const float* __restrict__ Wo,
                                                    const float* __restrict__ scale,
                                                    short* __restrict__ WtHi,
                                                    short* __restrict__ WtLo,
                                                    short* __restrict__ WoB) {
  const int blk = blockIdx.x, tid = threadIdx.x;
  if (blk < 96) {
    float v = Wt[blk * C_ + tid];
    if (blk >= 32 && blk < 64) v *= 1.44269504f;  // log2(e) into Q
    const short h = f2bf(v);
    WtHi[blk * C_ + tid] = h;
    WtLo[blk * C_ + tid] = f2bf(v - bf2f(h));
  } else {
    const int idx = (blk - 96) * 256 + tid;
    WoB[idx] = f2bf(Wo[idx] * scale[0]);
  }
}

// ---------------------------------------------------------------------------
// Kernel 1: QKV projection, pure MFMA, no LDS, x prefetched one chunk ahead.
// Epilogue writes directly into fragment-major Kf/Qf/Vf (scattered 2B
// stores, same count as before -- the scatter cost moves HERE, once,
// instead of being paid on every flash_attn fragment load).
// ---------------------------------------------------------------------------
__global__ __launch_bounds__(256) void qkv_mfma(const float* __restrict__ x,
                                                const short* __restrict__ WtHi,
                                                const short* __restrict__ WtLo,
                                                short* __restrict__ Kf,
                                                short* __restrict__ Qf,
                                                short* __restrict__ Vf) {
  const int b = blockIdx.y;
  const int tid = threadIdx.x;
  const int wave = tid >> 6, lane = tid & 63;
  const int col = lane & 15, quad = lane >> 4;
  const int n0 = (blockIdx.x * 4 + wave) * 16;

  const f32x4 z4 = {0.f, 0.f, 0.f, 0.f};
  f32x4 acc[6] = {z4, z4, z4, z4, z4, z4};  // 0..3 = KQ o-tiles, 4..5 = V

  const float* xb = x + (size_t)b * C_ * N_ + n0 + col;
  float xcur[8], xnxt[8];
#pragma unroll
  for (int j = 0; j < 8; ++j) xcur[j] = xb[(size_t)(quad * 8 + j) * N_];

#pragma unroll 2
  for (int c0 = 0; c0 < C_; c0 += 32) {
    if (c0 < C_ - 32) {
#pragma unroll
      for (int j = 0; j < 8; ++j)
        xnxt[j] = xb[(size_t)(c0 + 32 + quad * 8 + j) * N_];
    }
    bf16x8 xh, xl;
#pragma unroll
    for (int j = 0; j < 8; ++j) {
      const short h = (short)(__float_as_uint(xcur[j]) >> 16);  // trunc hi
      xh[j] = h;
      xl[j] = f2bf_r(xcur[j] - bf2f(h));
    }
#pragma unroll
    for (int ot = 0; ot < 4; ++ot) {  // K/Q: B-operand = Wt rows 0..63
      const int off = (ot * 16 + col) * C_ + c0 + quad * 8;
      const bf16x8 bh = *(const bf16x8*)(WtHi + off);
      const bf16x8 bl = *(const bf16x8*)(WtLo + off);
      acc[ot] = __builtin_amdgcn_mfma_f32_16x16x32_bf16(xh, bh, acc[ot], 0, 0, 0);
      acc[ot] = __builtin_amdgcn_mfma_f32_16x16x32_bf16(xl, bh, acc[ot], 0, 0, 0);
      acc[ot] = __builtin_amdgcn_mfma_f32_16x16x32_bf16(xh, bl, acc[ot], 0, 0, 0);
    }
#pragma unroll
    for (int ct = 0; ct < 2; ++ct) {  // V: A-operand = Wt rows 64..95
      const int off = ((64 + ct * 16) + col) * C_ + c0 + quad * 8;
      const bf16x8 ah = *(const bf16x8*)(WtHi + off);
      const bf16x8 al = *(const bf16x8*)(WtLo + off);
      acc[4 + ct] = __builtin_amdgcn_mfma_f32_16x16x32_bf16(ah, xh, acc[4 + ct], 0, 0, 0);
      acc[4 + ct] = __builtin_amdgcn_mfma_f32_16x16x32_bf16(ah, xl, acc[4 + ct], 0, 0, 0);
      acc[4 + ct] = __builtin_amdgcn_mfma_f32_16x16x32_bf16(al, xh, acc[4 + ct], 0, 0, 0);
    }
#pragma unroll
    for (int j = 0; j < 8; ++j) xcur[j] = xnxt[j];
  }

  // K epilogue (ot 0..1): D row=(quad*4+r)+n0 = key i, col-dim = c
#pragma unroll
  for (int ot = 0; ot < 2; ++ot)
#pragma unroll
    for (int r = 0; r < 4; ++r) {
      const int i = n0 + quad * 4 + r;
      const int c = ot * 16 + col;
      const int ln = (i & 31) | (((c >> 3) & 1) << 5);
      Kf[(((size_t)(b * 128 + (i >> 5)) * 2 + (c >> 4)) * 64 + ln) * 8 + (c & 7)] =
          f2bf(acc[ot][r]);
    }
  // Q epilogue (ot 2..3): col j = n, c = o-32
#pragma unroll
  for (int ot = 2; ot < 4; ++ot)
#pragma unroll
    for (int r = 0; r < 4; ++r) {
      const int j = n0 + quad * 4 + r;
      const int c = (ot - 2) * 16 + col;
      const int ln = (j & 31) | (((c >> 3) & 1) << 5);
      Qf[(((size_t)(b * 128 + (j >> 5)) * 2 + (c >> 4)) * 64 + ln) * 8 + (c & 7)] =
          f2bf(acc[ot][r]);
    }
  // V epilogue: c = ct*16+quad*4+r, key n = n0+col
#pragma unroll
  for (int ct = 0; ct < 2; ++ct)
#pragma unroll
    for (int r = 0; r < 4; ++r) {
      const int c = ct * 16 + quad * 4 + r;
      const int n = n0 + col;
      const int ln = c | (((n >> 3) & 1) << 5);
      Vf[((size_t)(b * 256 + (n >> 4)) * 64 + ln) * 8 + (n & 7)] =
          f2bf(acc[4 + ct][r]);
    }
}

// ---------------------------------------------------------------------------
// Kernel 2: 32x32-MFMA flash attention, zero LDS, fragment-major inputs.
// Wave = one 32-col j-tile x one KV-quarter (1024 keys = 32 tiles of 32).
// Grid (128 jb, 4 quarters, 8 b) = 4096 single-wave blocks = 4 waves/SIMD.
// ALL hot loads are now coalesced 1KB dwordx4 (lane l reads base + l*16):
// per tile 4 loads (ka,kb,va,vb) + 1-tile-deep register prefetch restores
// the ILP that round 4 dropped.  Est ~100 unified regs -> fits the
// 128-budget of __launch_bounds__(64,4) (R1/R3 spilled at ~140 demand).
// Tripwire: WRITE_SIZE must stay ~8.7 MB; growth = spill, revert bound.
// Last-iter prefetch overreads into the adjacent ws buffer -- harmless.
// ---------------------------------------------------------------------------
__global__ __launch_bounds__(64, 4) void flash_attn(const short* __restrict__ Kf,
                                                    const short* __restrict__ Qf,
                                                    const short* __restrict__ Vf,
                                                    short* __restrict__ OPart,
                                                    float* __restrict__ LPart) {
  const int b = blockIdx.z, hq = blockIdx.y;  // hq = KV quarter, 0..3
  const int jt = blockIdx.x;                  // 32-col j-tile, 0..127
  const int lane = threadIdx.x;
  const int j32 = lane & 31, h32 = lane >> 5;

  const f32x16 z16 = {0.f};
  // Q B-frags, loop-invariant, coalesced
  const short* pQ = Qf + ((size_t)(b * 128 + jt) * 2) * 512 + lane * 8;
  const bf16x8 qf0 = *(const bf16x8*)(pQ);
  const bf16x8 qf1 = *(const bf16x8*)(pQ + 512);

  const short* pK = Kf + ((size_t)(b * 128 + hq * 32) * 2) * 512 + lane * 8;
  const short* pV = Vf + ((size_t)(b * 256 + hq * 64)) * 512 + lane * 8;

  f32x16 acc = z16;
  float ps = 0.f;

  bf16x8 ka = *(const bf16x8*)(pK);
  bf16x8 kb = *(const bf16x8*)(pK + 512);
  bf16x8 va = *(const bf16x8*)(pV);
  bf16x8 vb = *(const bf16x8*)(pV + 512);

#pragma unroll 1
  for (int t = 0; t < 32; ++t) {
    pK += 1024;
    pV += 1024;
    // prefetch next 32-key tile (coalesced; unused garbage on last iter)
    const bf16x8 kan = *(const bf16x8*)(pK);
    const bf16x8 kbn = *(const bf16x8*)(pK + 512);
    const bf16x8 van = *(const bf16x8*)(pV);
    const bf16x8 vbn = *(const bf16x8*)(pV + 512);

    // ---- S tile (32 i x 32 j), k=32 over two chunks ----
    __builtin_amdgcn_s_setprio(1);
    f32x16 s = __builtin_amdgcn_mfma_f32_32x32x16_bf16(ka, qf0, z16, 0, 0, 0);
    s = __builtin_amdgcn_mfma_f32_32x32x16_bf16(kb, qf1, s, 0, 0, 0);
    __builtin_amdgcn_s_setprio(0);
    // ---- p = exp2(s); l tree; pack row-pairs into dwords ----
    float p[16];
#pragma unroll
    for (int r = 0; r < 16; ++r) p[r] = __builtin_amdgcn_exp2f(s[r]);
    ps += (((p[0] + p[1]) + (p[2] + p[3])) + ((p[4] + p[5]) + (p[6] + p[7]))) +
          (((p[8] + p[9]) + (p[10] + p[11])) + ((p[12] + p[13]) + (p[14] + p[15])));
    unsigned d[8];
#pragma unroll
    for (int k = 0; k < 8; ++k) {
      const unsigned u0 = __float_as_uint(p[2 * k]) + 0x8000u;
      const unsigned u1 = __float_as_uint(p[2 * k + 1]) + 0x8000u;
      d[k] = __builtin_amdgcn_perm(u1, u0, 0x07060302u);  // (bf16 odd)<<16 | bf16 even
    }
    // ---- B-frags for PV: rows [8*h32, 8*h32+8) of each 16-row chunk ----
    union { unsigned u[4]; bf16x8 v; } f0, f1;
#ifdef HAVE_PLSWAP
    {
      const uint32x2 r0 = __builtin_amdgcn_permlane32_swap(d[0], d[2], false, false);
      f0.u[0] = r0[0]; f0.u[2] = r0[1];
      const uint32x2 r1 = __builtin_amdgcn_permlane32_swap(d[1], d[3], false, false);
      f0.u[1] = r1[0]; f0.u[3] = r1[1];
      const uint32x2 r2 = __builtin_amdgcn_permlane32_swap(d[4], d[6], false, false);
      f1.u[0] = r2[0]; f1.u[2] = r2[1];
      const uint32x2 r3 = __builtin_amdgcn_permlane32_swap(d[5], d[7], false, false);
      f1.u[1] = r3[0]; f1.u[3] = r3[1];
    }
#else
    {
      unsigned xw[8];
#pragma unroll
      for (int k = 0; k < 8; ++k) xw[k] = __shfl_xor((int)d[k], 32);
      f0.u[0] = h32 ? xw[2] : d[0];
      f0.u[1] = h32 ? xw[3] : d[1];
      f0.u[2] = h32 ? d[2] : xw[0];
      f0.u[3] = h32 ? d[3] : xw[1];
      f1.u[0] = h32 ? xw[6] : d[4];
      f1.u[1] = h32 ? xw[7] : d[5];
      f1.u[2] = h32 ? d[6] : xw[4];
      f1.u[3] = h32 ? d[7] : xw[5];
    }
#endif
    // ---- O += V @ P ----
    __builtin_amdgcn_s_setprio(1);
    acc = __builtin_amdgcn_mfma_f32_32x32x16_bf16(va, f0.v, acc, 0, 0, 0);
    acc = __builtin_amdgcn_mfma_f32_32x32x16_bf16(vb, f1.v, acc, 0, 0, 0);
    __builtin_amdgcn_s_setprio(0);

    ka = kan; kb = kbn; va = van; vb = vbn;
  }

  // ---- epilogue: finish l across halves, write O/l partials ----
  const size_t base = ((size_t)b * NH_ + hq) * N_;
  const float l = ps + __shfl_xor(ps, 32);
  const int jg = jt * 32 + j32;
  if (h32 == 0) LPart[base + jg] = l;
  short* OP = OPart + (base + jg) * 32;
#pragma unroll
  for (int g = 0; g < 4; ++g) {  // regs 4g..4g+3 -> c = 8g + 4*h32 + 0..3
    bf16x4 o = {f2bf(acc[4 * g + 0]), f2bf(acc[4 * g + 1]),
                f2bf(acc[4 * g + 2]), f2bf(acc[4 * g + 3])};
    *(bf16x4*)(OP + 8 * g + 4 * h32) = o;
  }
}

// ---------------------------------------------------------------------------
// Kernel 3: merge 4 KV-quarter partials, normalize, out-proj, residual.
// Grid (64 n-blocks, 2 co-halves, 8 b) = 1024 blocks.
// out[b,co,n] = WoB @ (sum_h O_h / sum_h l_h) + x
// ---------------------------------------------------------------------------
__global__ __launch_bounds__(256) void out_proj(const short* __restrict__ OPart,
                                                const float* __restrict__ LPart,
                                                const short* __restrict__ WoB,
                                                const float* __restrict__ x,
                                                float* __restrict__ out) {
  const int b = blockIdx.z, chalf = blockIdx.y;
  const int tid = threadIdx.x;
  const int wave = tid >> 6, lane = tid & 63;
  const int col = lane & 15, quad = lane >> 4;
  const int jg = blockIdx.x * 64 + wave * 16 + col;  // global n/j
  const int n0 = blockIdx.x * 64 + wave * 16;

  float osum[8];
#pragma unroll
  for (int e = 0; e < 8; ++e) osum[e] = 0.f;
  float lsum = 0.f;
#pragma unroll
  for (int h = 0; h < NH_; ++h) {
    const size_t p = ((size_t)b * NH_ + h) * N_ + jg;
    const bf16x8 o = *(const bf16x8*)(OPart + p * 32 + quad * 8);
#pragma unroll
    for (int e = 0; e < 8; ++e) osum[e] += bf2f(o[e]);
    lsum += LPart[p];
  }
  const float linv = 1.f / lsum;
  bf16x8 bf;
#pragma unroll
  for (int e = 0; e < 8; ++e) bf[e] = f2bf(osum[e] * linv);

  const f32x4 z4 = {0.f, 0.f, 0.f, 0.f};
  const float* xb = x + (size_t)b * C_ * N_;
  float* ob = out + (size_t)b * C_ * N_;
#pragma unroll
  for (int ct = 0; ct < 8; ++ct) {
    const int ctg = chalf * 8 + ct;
    const bf16x8 af = *(const bf16x8*)(WoB + (ctg * 16 + col) * 32 + quad * 8);
    const f32x4 a = __builtin_amdgcn_mfma_f32_16x16x32_bf16(af, bf, z4, 0, 0, 0);
#pragma unroll
    for (int r = 0; r < 4; ++r) {
      const size_t idx = (size_t)(ctg * 16 + quad * 4 + r) * N_ + n0 + col;
      ob[idx] = a[r] + xb[idx];
    }
  }
}

// ---------------------------------------------------------------------------
extern "C" void kernel_launch(void* const* d_in, const int* in_sizes, int n_in,
                              void* d_out, int out_size, void* d_ws,
                              size_t ws_size, hipStream_t stream) {
  const float* x = (const float*)d_in[0];      // [8,256,64,64]
  const float* Wt = (const float*)d_in[1];     // [96,256]
  const float* Wo = (const float*)d_in[2];     // [256,32]
  const float* scale = (const float*)d_in[3];  // [1]
  float* out = (float*)d_out;

  // ws: OPart bf16 [8][4][4096][32] (8.4 MB) | LPart f32 [8][4][4096] (0.5 MB)
  //   | Kf (2 MB) | Qf (2 MB) | Vf (2 MB) | WtHi | WtLo | WoB  (~15 MB)
  short* OPart = (short*)d_ws;
  float* LPart = (float*)(OPart + (size_t)B_ * NH_ * N_ * 32);
  short* Kf = (short*)(LPart + (size_t)B_ * NH_ * N_);
  short* Qf = Kf + (size_t)B_ * 128 * 1024;
  short* Vf = Qf + (size_t)B_ * 128 * 1024;
  short* WtHi = Vf + (size_t)B_ * 256 * 512;
  short* WtLo = WtHi + 96 * C_;
  short* WoB = WtLo + 96 * C_;

  prep_weights<<<dim3(128), 256, 0, stream>>>(Wt, Wo, scale, WtHi, WtLo, WoB);
  qkv_mfma<<<dim3(64, B_), 256, 0, stream>>>(x, WtHi, WtLo, Kf, Qf, Vf);
  flash_attn<<<dim3(128, NH_, B_), 64, 0, stream>>>(Kf, Qf, Vf, OPart, LPart);
  out_proj<<<dim3(64, 2, B_), 256, 0, stream>>>(OPart, LPart, WoB, x, out);
}

// Round 6
// 152.156 us; speedup vs baseline: 1.4527x; 1.0007x over previous
//
#include <hip/hip_runtime.h>
#include <math.h>

// Problem constants: B=8, C=256, CR=32, N=4096 (=64*64)
#define B_ 8
#define C_ 256
#define CR_ 32
#define N_ 4096
#define NH_ 4  // KV split factor (quarters)

typedef __attribute__((ext_vector_type(8))) short bf16x8;   // MFMA A/B frag
typedef __attribute__((ext_vector_type(4))) short bf16x4;
typedef __attribute__((ext_vector_type(4))) float f32x4;    // 16x16 C/D frag
typedef __attribute__((ext_vector_type(16))) float f32x16;  // 32x32 C/D frag
typedef __attribute__((ext_vector_type(2))) unsigned uint32x2;

#if defined(__has_builtin)
#if __has_builtin(__builtin_amdgcn_permlane32_swap)
#define HAVE_PLSWAP 1
#endif
#endif

__device__ inline short f2bf(float f) {  // RTNE
  union { float f; unsigned u; } v; v.f = f;
  unsigned r = v.u + 0x7FFFu + ((v.u >> 16) & 1u);
  return (short)(r >> 16);
}
__device__ inline float bf2f(short h) {
  union { unsigned u; float f; } v; v.u = ((unsigned)(unsigned short)h) << 16;
  return v.f;
}
__device__ inline short f2bf_r(float f) {  // cheap round for hot paths
  return (short)((__float_as_uint(f) + 0x8000u) >> 16);
}

// ---------------------------------------------------------------------------
// FRAGMENT-MAJOR LAYOUTS (round-5, kept).  All flash_attn hot loads are
// coalesced 1KB dwordx4: lane l reads base + l*16.
//   Kf[b][kt=0..127][ch=0..1][lane=0..63][e=0..7]  (A-frag: key=kt*32+(l&31),
//       c = ch*16 + (l>>5)*8 + e)
//   Qf[b][jt=0..127][ch=0..1][lane][e]             (B-frag: col=jt*32+(l&31),
//       c = ch*16 + (l>>5)*8 + e)
//   Vf[b][n16=0..255][lane][e]                     (A-frag: c=(l&31),
//       key = n16*16 + (l>>5)*8 + e)
// ROUND-6: flash wave now owns TWO j-tiles (R0's ILP structure) on top of
// the coalesced layout.  Rationale: occupancy classes are pow2 (m69 + R2
// evidence: 140 regs -> 2 waves/SIMD, no 3-wave class), so the choice is
// 1 jt @ <=128 regs (4 waves, R5, ~38us) vs 2 jt @ ~140-160 (2 waves).
// 2 jt gives the same independent-chain count per SIMD (2 waves x 2 chains)
// while HALVING K/V load traffic (each K/V tile feeds 2 S-tiles).
// ---------------------------------------------------------------------------

// ---------------------------------------------------------------------------
// Kernel 0: weight prep.  WtHi/WtLo = split-bf16 of Wt (log2e folded into Q
// rows 32..63 so softmax runs in exp2 domain).  WoB = bf16(Wo * scale).
// ---------------------------------------------------------------------------
__global__ __launch_bounds__(256) void prep_weights(const float* __restrict__ Wt,
                                                    const float* __restrict__ Wo,
                                                    const float* __restrict__ scale,
                                                    short* __restrict__ WtHi,
                                                    short* __restrict__ WtLo,
                                                    short* __restrict__ WoB) {
  const int blk = blockIdx.x, tid = threadIdx.x;
  if (blk < 96) {
    float v = Wt[blk * C_ + tid];
    if (blk >= 32 && blk < 64) v *= 1.44269504f;  // log2(e) into Q
    const short h = f2bf(v);
    WtHi[blk * C_ + tid] = h;
    WtLo[blk * C_ + tid] = f2bf(v - bf2f(h));
  } else {
    const int idx = (blk - 96) * 256 + tid;
    WoB[idx] = f2bf(Wo[idx] * scale[0]);
  }
}

// ---------------------------------------------------------------------------
// Kernel 1: QKV projection, pure MFMA, no LDS, x prefetched one chunk ahead.
// Epilogue writes directly into fragment-major Kf/Qf/Vf (scattered 2B
// stores, paid once here instead of on every flash_attn fragment load).
// ---------------------------------------------------------------------------
__global__ __launch_bounds__(256) void qkv_mfma(const float* __restrict__ x,
                                                const short* __restrict__ WtHi,
                                                const short* __restrict__ WtLo,
                                                short* __restrict__ Kf,
                                                short* __restrict__ Qf,
                                                short* __restrict__ Vf) {
  const int b = blockIdx.y;
  const int tid = threadIdx.x;
  const int wave = tid >> 6, lane = tid & 63;
  const int col = lane & 15, quad = lane >> 4;
  const int n0 = (blockIdx.x * 4 + wave) * 16;

  const f32x4 z4 = {0.f, 0.f, 0.f, 0.f};
  f32x4 acc[6] = {z4, z4, z4, z4, z4, z4};  // 0..3 = KQ o-tiles, 4..5 = V

  const float* xb = x + (size_t)b * C_ * N_ + n0 + col;
  float xcur[8], xnxt[8];
#pragma unroll
  for (int j = 0; j < 8; ++j) xcur[j] = xb[(size_t)(quad * 8 + j) * N_];

#pragma unroll 2
  for (int c0 = 0; c0 < C_; c0 += 32) {
    if (c0 < C_ - 32) {
#pragma unroll
      for (int j = 0; j < 8; ++j)
        xnxt[j] = xb[(size_t)(c0 + 32 + quad * 8 + j) * N_];
    }
    bf16x8 xh, xl;
#pragma unroll
    for (int j = 0; j < 8; ++j) {
      const short h = (short)(__float_as_uint(xcur[j]) >> 16);  // trunc hi
      xh[j] = h;
      xl[j] = f2bf_r(xcur[j] - bf2f(h));
    }
#pragma unroll
    for (int ot = 0; ot < 4; ++ot) {  // K/Q: B-operand = Wt rows 0..63
      const int off = (ot * 16 + col) * C_ + c0 + quad * 8;
      const bf16x8 bh = *(const bf16x8*)(WtHi + off);
      const bf16x8 bl = *(const bf16x8*)(WtLo + off);
      acc[ot] = __builtin_amdgcn_mfma_f32_16x16x32_bf16(xh, bh, acc[ot], 0, 0, 0);
      acc[ot] = __builtin_amdgcn_mfma_f32_16x16x32_bf16(xl, bh, acc[ot], 0, 0, 0);
      acc[ot] = __builtin_amdgcn_mfma_f32_16x16x32_bf16(xh, bl, acc[ot], 0, 0, 0);
    }
#pragma unroll
    for (int ct = 0; ct < 2; ++ct) {  // V: A-operand = Wt rows 64..95
      const int off = ((64 + ct * 16) + col) * C_ + c0 + quad * 8;
      const bf16x8 ah = *(const bf16x8*)(WtHi + off);
      const bf16x8 al = *(const bf16x8*)(WtLo + off);
      acc[4 + ct] = __builtin_amdgcn_mfma_f32_16x16x32_bf16(ah, xh, acc[4 + ct], 0, 0, 0);
      acc[4 + ct] = __builtin_amdgcn_mfma_f32_16x16x32_bf16(ah, xl, acc[4 + ct], 0, 0, 0);
      acc[4 + ct] = __builtin_amdgcn_mfma_f32_16x16x32_bf16(al, xh, acc[4 + ct], 0, 0, 0);
    }
#pragma unroll
    for (int j = 0; j < 8; ++j) xcur[j] = xnxt[j];
  }

  // K epilogue (ot 0..1): D row=(quad*4+r)+n0 = key i, col-dim = c
#pragma unroll
  for (int ot = 0; ot < 2; ++ot)
#pragma unroll
    for (int r = 0; r < 4; ++r) {
      const int i = n0 + quad * 4 + r;
      const int c = ot * 16 + col;
      const int ln = (i & 31) | (((c >> 3) & 1) << 5);
      Kf[(((size_t)(b * 128 + (i >> 5)) * 2 + (c >> 4)) * 64 + ln) * 8 + (c & 7)] =
          f2bf(acc[ot][r]);
    }
  // Q epilogue (ot 2..3): col j = n, c = o-32
#pragma unroll
  for (int ot = 2; ot < 4; ++ot)
#pragma unroll
    for (int r = 0; r < 4; ++r) {
      const int j = n0 + quad * 4 + r;
      const int c = (ot - 2) * 16 + col;
      const int ln = (j & 31) | (((c >> 3) & 1) << 5);
      Qf[(((size_t)(b * 128 + (j >> 5)) * 2 + (c >> 4)) * 64 + ln) * 8 + (c & 7)] =
          f2bf(acc[ot][r]);
    }
  // V epilogue: c = ct*16+quad*4+r, key n = n0+col
#pragma unroll
  for (int ct = 0; ct < 2; ++ct)
#pragma unroll
    for (int r = 0; r < 4; ++r) {
      const int c = ct * 16 + quad * 4 + r;
      const int n = n0 + col;
      const int ln = c | (((n >> 3) & 1) << 5);
      Vf[((size_t)(b * 256 + (n >> 4)) * 64 + ln) * 8 + (n & 7)] =
          f2bf(acc[4 + ct][r]);
    }
}

// ---------------------------------------------------------------------------
// Kernel 2: 32x32-MFMA flash attention, zero LDS, fragment-major inputs,
// TWO j-tiles per wave (64 query cols) x one KV-quarter (1024 keys = 32
// tiles of 32).  Grid (64 jb, 4 quarters, 8 b) = 2048 single-wave blocks
// = 2 waves/SIMD.  Each coalesced K/V tile load feeds BOTH j-tiles' S/PV
// chains: 2 independent chains per wave x 2 waves = 4 chains/SIMD (same
// as R5) at HALF the load traffic.  Est ~140-160 unified regs -> 2-wave
// occupancy class; no launch-bound coercion so no spill is possible.
// Tripwire: WRITE_SIZE must stay ~8.7 MB (OPart+LPart); growth = spill.
// Last-iter prefetch overreads into the adjacent ws buffer -- harmless.
// ---------------------------------------------------------------------------
__global__ __launch_bounds__(64, 2) void flash_attn(const short* __restrict__ Kf,
                                                    const short* __restrict__ Qf,
                                                    const short* __restrict__ Vf,
                                                    short* __restrict__ OPart,
                                                    float* __restrict__ LPart) {
  const int b = blockIdx.z, hq = blockIdx.y;  // hq = KV quarter, 0..3
  const int jb = blockIdx.x;                  // 64-col j-block = 2 j-tiles
  const int lane = threadIdx.x;
  const int j32 = lane & 31, h32 = lane >> 5;

  const f32x16 z16 = {0.f};
  // Q B-frags for both j-tiles, loop-invariant, coalesced
  const short* pQ = Qf + ((size_t)(b * 128 + jb * 2) * 2) * 512 + lane * 8;
  bf16x8 qf[2][2];
  qf[0][0] = *(const bf16x8*)(pQ);
  qf[0][1] = *(const bf16x8*)(pQ + 512);
  qf[1][0] = *(const bf16x8*)(pQ + 1024);
  qf[1][1] = *(const bf16x8*)(pQ + 1536);

  const short* pK = Kf + ((size_t)(b * 128 + hq * 32) * 2) * 512 + lane * 8;
  const short* pV = Vf + ((size_t)(b * 256 + hq * 64)) * 512 + lane * 8;

  f32x16 acc[2] = {z16, z16};
  float ps[2] = {0.f, 0.f};

  bf16x8 ka = *(const bf16x8*)(pK);
  bf16x8 kb = *(const bf16x8*)(pK + 512);
  bf16x8 va = *(const bf16x8*)(pV);
  bf16x8 vb = *(const bf16x8*)(pV + 512);

#pragma unroll 1
  for (int t = 0; t < 32; ++t) {
    pK += 1024;
    pV += 1024;
    // prefetch next 32-key tile (coalesced; unused garbage on last iter)
    const bf16x8 kan = *(const bf16x8*)(pK);
    const bf16x8 kbn = *(const bf16x8*)(pK + 512);
    const bf16x8 van = *(const bf16x8*)(pV);
    const bf16x8 vbn = *(const bf16x8*)(pV + 512);

#pragma unroll
    for (int jt = 0; jt < 2; ++jt) {
      // ---- S tile (32 i x 32 j), k=32 over two chunks ----
      __builtin_amdgcn_s_setprio(1);
      f32x16 s = __builtin_amdgcn_mfma_f32_32x32x16_bf16(ka, qf[jt][0], z16, 0, 0, 0);
      s = __builtin_amdgcn_mfma_f32_32x32x16_bf16(kb, qf[jt][1], s, 0, 0, 0);
      __builtin_amdgcn_s_setprio(0);
      // ---- p = exp2(s); l tree; pack row-pairs into dwords ----
      float p[16];
#pragma unroll
      for (int r = 0; r < 16; ++r) p[r] = __builtin_amdgcn_exp2f(s[r]);
      ps[jt] += (((p[0] + p[1]) + (p[2] + p[3])) + ((p[4] + p[5]) + (p[6] + p[7]))) +
                (((p[8] + p[9]) + (p[10] + p[11])) + ((p[12] + p[13]) + (p[14] + p[15])));
      unsigned d[8];
#pragma unroll
      for (int k = 0; k < 8; ++k) {
        const unsigned u0 = __float_as_uint(p[2 * k]) + 0x8000u;
        const unsigned u1 = __float_as_uint(p[2 * k + 1]) + 0x8000u;
        d[k] = __builtin_amdgcn_perm(u1, u0, 0x07060302u);  // (bf16 odd)<<16 | bf16 even
      }
      // ---- B-frags for PV: rows [8*h32, 8*h32+8) of each 16-row chunk ----
      union { unsigned u[4]; bf16x8 v; } f0, f1;
#ifdef HAVE_PLSWAP
      {
        const uint32x2 r0 = __builtin_amdgcn_permlane32_swap(d[0], d[2], false, false);
        f0.u[0] = r0[0]; f0.u[2] = r0[1];
        const uint32x2 r1 = __builtin_amdgcn_permlane32_swap(d[1], d[3], false, false);
        f0.u[1] = r1[0]; f0.u[3] = r1[1];
        const uint32x2 r2 = __builtin_amdgcn_permlane32_swap(d[4], d[6], false, false);
        f1.u[0] = r2[0]; f1.u[2] = r2[1];
        const uint32x2 r3 = __builtin_amdgcn_permlane32_swap(d[5], d[7], false, false);
        f1.u[1] = r3[0]; f1.u[3] = r3[1];
      }
#else
      {
        unsigned xw[8];
#pragma unroll
        for (int k = 0; k < 8; ++k) xw[k] = __shfl_xor((int)d[k], 32);
        f0.u[0] = h32 ? xw[2] : d[0];
        f0.u[1] = h32 ? xw[3] : d[1];
        f0.u[2] = h32 ? d[2] : xw[0];
        f0.u[3] = h32 ? d[3] : xw[1];
        f1.u[0] = h32 ? xw[6] : d[4];
        f1.u[1] = h32 ? xw[7] : d[5];
        f1.u[2] = h32 ? d[6] : xw[4];
        f1.u[3] = h32 ? d[7] : xw[5];
      }
#endif
      // ---- O += V @ P ----
      __builtin_amdgcn_s_setprio(1);
      acc[jt] = __builtin_amdgcn_mfma_f32_32x32x16_bf16(va, f0.v, acc[jt], 0, 0, 0);
      acc[jt] = __builtin_amdgcn_mfma_f32_32x32x16_bf16(vb, f1.v, acc[jt], 0, 0, 0);
      __builtin_amdgcn_s_setprio(0);
    }

    ka = kan; kb = kbn; va = van; vb = vbn;
  }

  // ---- epilogue: finish l across halves, write O/l partials ----
  const size_t base = ((size_t)b * NH_ + hq) * N_;
#pragma unroll
  for (int jt = 0; jt < 2; ++jt) {
    const float l = ps[jt] + __shfl_xor(ps[jt], 32);
    const int jg = (jb * 2 + jt) * 32 + j32;
    if (h32 == 0) LPart[base + jg] = l;
    short* OP = OPart + (base + jg) * 32;
#pragma unroll
    for (int g = 0; g < 4; ++g) {  // regs 4g..4g+3 -> c = 8g + 4*h32 + 0..3
      bf16x4 o = {f2bf(acc[jt][4 * g + 0]), f2bf(acc[jt][4 * g + 1]),
                  f2bf(acc[jt][4 * g + 2]), f2bf(acc[jt][4 * g + 3])};
      *(bf16x4*)(OP + 8 * g + 4 * h32) = o;
    }
  }
}

// ---------------------------------------------------------------------------
// Kernel 3: merge 4 KV-quarter partials, normalize, out-proj, residual.
// Grid (64 n-blocks, 2 co-halves, 8 b) = 1024 blocks.
// out[b,co,n] = WoB @ (sum_h O_h / sum_h l_h) + x
// ---------------------------------------------------------------------------
__global__ __launch_bounds__(256) void out_proj(const short* __restrict__ OPart,
                                                const float* __restrict__ LPart,
                                                const short* __restrict__ WoB,
                                                const float* __restrict__ x,
                                                float* __restrict__ out) {
  const int b = blockIdx.z, chalf = blockIdx.y;
  const int tid = threadIdx.x;
  const int wave = tid >> 6, lane = tid & 63;
  const int col = lane & 15, quad = lane >> 4;
  const int jg = blockIdx.x * 64 + wave * 16 + col;  // global n/j
  const int n0 = blockIdx.x * 64 + wave * 16;

  float osum[8];
#pragma unroll
  for (int e = 0; e < 8; ++e) osum[e] = 0.f;
  float lsum = 0.f;
#pragma unroll
  for (int h = 0; h < NH_; ++h) {
    const size_t p = ((size_t)b * NH_ + h) * N_ + jg;
    const bf16x8 o = *(const bf16x8*)(OPart + p * 32 + quad * 8);
#pragma unroll
    for (int e = 0; e < 8; ++e) osum[e] += bf2f(o[e]);
    lsum += LPart[p];
  }
  const float linv = 1.f / lsum;
  bf16x8 bf;
#pragma unroll
  for (int e = 0; e < 8; ++e) bf[e] = f2bf(osum[e] * linv);

  const f32x4 z4 = {0.f, 0.f, 0.f, 0.f};
  const float* xb = x + (size_t)b * C_ * N_;
  float* ob = out + (size_t)b * C_ * N_;
#pragma unroll
  for (int ct = 0; ct < 8; ++ct) {
    const int ctg = chalf * 8 + ct;
    const bf16x8 af = *(const bf16x8*)(WoB + (ctg * 16 + col) * 32 + quad * 8);
    const f32x4 a = __builtin_amdgcn_mfma_f32_16x16x32_bf16(af, bf, z4, 0, 0, 0);
#pragma unroll
    for (int r = 0; r < 4; ++r) {
      const size_t idx = (size_t)(ctg * 16 + quad * 4 + r) * N_ + n0 + col;
      ob[idx] = a[r] + xb[idx];
    }
  }
}

// ---------------------------------------------------------------------------
extern "C" void kernel_launch(void* const* d_in, const int* in_sizes, int n_in,
                              void* d_out, int out_size, void* d_ws,
                              size_t ws_size, hipStream_t stream) {
  const float* x = (const float*)d_in[0];      // [8,256,64,64]
  const float* Wt = (const float*)d_in[1];     // [96,256]
  const float* Wo = (const float*)d_in[2];     // [256,32]
  const float* scale = (const float*)d_in[3];  // [1]
  float* out = (float*)d_out;

  // ws: OPart bf16 [8][4][4096][32] (8.4 MB) | LPart f32 [8][4][4096] (0.5 MB)
  //   | Kf (2 MB) | Qf (2 MB) | Vf (2 MB) | WtHi | WtLo | WoB  (~15 MB)
  short* OPart = (short*)d_ws;
  float* LPart = (float*)(OPart + (size_t)B_ * NH_ * N_ * 32);
  short* Kf = (short*)(LPart + (size_t)B_ * NH_ * N_);
  short* Qf = Kf + (size_t)B_ * 128 * 1024;
  short* Vf = Qf + (size_t)B_ * 128 * 1024;
  short* WtHi = Vf + (size_t)B_ * 256 * 512;
  short* WtLo = WtHi + 96 * C_;
  short* WoB = WtLo + 96 * C_;

  prep_weights<<<dim3(128), 256, 0, stream>>>(Wt, Wo, scale, WtHi, WtLo, WoB);
  qkv_mfma<<<dim3(64, B_), 256, 0, stream>>>(x, WtHi, WtLo, Kf, Qf, Vf);
  flash_attn<<<dim3(64, NH_, B_), 64, 0, stream>>>(Kf, Qf, Vf, OPart, LPart);
  out_proj<<<dim3(64, 2, B_), 256, 0, stream>>>(OPart, LPart, WoB, x, out);
}

// Round 8
// 150.685 us; speedup vs baseline: 1.4669x; 1.0098x over previous
//
#include <hip/hip_runtime.h>
#include <math.h>

// Problem constants: B=8, C=256, CR=32, N=4096 (=64*64)
#define B_ 8
#define C_ 256
#define CR_ 32
#define N_ 4096
#define NH_ 4  // KV split factor (quarters)

typedef __attribute__((ext_vector_type(8))) short bf16x8;   // MFMA A/B frag
typedef __attribute__((ext_vector_type(4))) short bf16x4;
typedef __attribute__((ext_vector_type(4))) float f32x4;    // 16x16 C/D frag
typedef __attribute__((ext_vector_type(16))) float f32x16;  // 32x32 C/D frag
typedef __attribute__((ext_vector_type(2))) unsigned uint32x2;

#if defined(__has_builtin)
#if __has_builtin(__builtin_amdgcn_permlane32_swap)
#define HAVE_PLSWAP 1
#endif
#endif

__device__ inline short f2bf(float f) {  // RTNE
  union { float f; unsigned u; } v; v.f = f;
  unsigned r = v.u + 0x7FFFu + ((v.u >> 16) & 1u);
  return (short)(r >> 16);
}
__device__ inline float bf2f(short h) {
  union { unsigned u; float f; } v; v.u = ((unsigned)(unsigned short)h) << 16;
  return v.f;
}
__device__ inline short f2bf_r(float f) {  // cheap round for hot paths
  return (short)((__float_as_uint(f) + 0x8000u) >> 16);
}

// ---------------------------------------------------------------------------
// FRAGMENT-MAJOR LAYOUTS (round-5, kept).  All flash_attn hot loads are
// coalesced 1KB dwordx4: lane l reads base + l*16.
//   Kf[b][kt=0..127][ch=0..1][lane=0..63][e=0..7]  (A-frag: key=kt*32+(l&31),
//       c = ch*16 + (l>>5)*8 + e)
//   Qf[b][jt=0..127][ch=0..1][lane][e]             (B-frag: col=jt*32+(l&31),
//       c = ch*16 + (l>>5)*8 + e)
//   Vf[b][n16=0..255][lane][e]                     (A-frag: c=(l&31),
//       key = n16*16 + (l>>5)*8 + e)
// ROUND-8 = ROUND-7 RESUBMIT (round-7 bench was an infra failure, no data).
// Theory under test: R5 (1jt/4waves) == R6 (2jt/2waves) == ~38us -> wall is
// NOT occupancy/ILP.  FETCH_SIZE 24.8MB = 4x the 6MB K/Q/V footprint = HBM
// re-fetch: uncorrelated (b,hq) blocks round-robin over XCDs put a 4MB
// K/V working set on each 4MB L2 -> thrash -> ~500-900cyc load latency
// that a 1-deep prefetch can't cover.  Fix: (1) XCD-locality swizzle
// (all 64 j-blocks of one (b,hq) on one XCD; per-XCD set 512KB << L2),
// (2) 2-deep register prefetch (issue-to-use ~2 iters, covers L3 lat).
// ---------------------------------------------------------------------------

// ---------------------------------------------------------------------------
// Kernel 0: weight prep.  WtHi/WtLo = split-bf16 of Wt (log2e folded into Q
// rows 32..63 so softmax runs in exp2 domain).  WoB = bf16(Wo * scale).
// ---------------------------------------------------------------------------
__global__ __launch_bounds__(256) void prep_weights(const float* __restrict__ Wt,
                                                    const float* __restrict__ Wo,
                                                    const float* __restrict__ scale,
                                                    short* __restrict__ WtHi,
                                                    short* __restrict__ WtLo,
                                                    short* __restrict__ WoB) {
  const int blk = blockIdx.x, tid = threadIdx.x;
  if (blk < 96) {
    float v = Wt[blk * C_ + tid];
    if (blk >= 32 && blk < 64) v *= 1.44269504f;  // log2(e) into Q
    const short h = f2bf(v);
    WtHi[blk * C_ + tid] = h;
    WtLo[blk * C_ + tid] = f2bf(v - bf2f(h));
  } else {
    const int idx = (blk - 96) * 256 + tid;
    WoB[idx] = f2bf(Wo[idx] * scale[0]);
  }
}

// ---------------------------------------------------------------------------
// Kernel 1: QKV projection, pure MFMA, no LDS, x prefetched one chunk ahead.
// Epilogue writes directly into fragment-major Kf/Qf/Vf (scattered 2B
// stores, paid once here instead of on every flash_attn fragment load).
// ---------------------------------------------------------------------------
__global__ __launch_bounds__(256) void qkv_mfma(const float* __restrict__ x,
                                                const short* __restrict__ WtHi,
                                                const short* __restrict__ WtLo,
                                                short* __restrict__ Kf,
                                                short* __restrict__ Qf,
                                                short* __restrict__ Vf) {
  const int b = blockIdx.y;
  const int tid = threadIdx.x;
  const int wave = tid >> 6, lane = tid & 63;
  const int col = lane & 15, quad = lane >> 4;
  const int n0 = (blockIdx.x * 4 + wave) * 16;

  const f32x4 z4 = {0.f, 0.f, 0.f, 0.f};
  f32x4 acc[6] = {z4, z4, z4, z4, z4, z4};  // 0..3 = KQ o-tiles, 4..5 = V

  const float* xb = x + (size_t)b * C_ * N_ + n0 + col;
  float xcur[8], xnxt[8];
#pragma unroll
  for (int j = 0; j < 8; ++j) xcur[j] = xb[(size_t)(quad * 8 + j) * N_];

#pragma unroll 2
  for (int c0 = 0; c0 < C_; c0 += 32) {
    if (c0 < C_ - 32) {
#pragma unroll
      for (int j = 0; j < 8; ++j)
        xnxt[j] = xb[(size_t)(c0 + 32 + quad * 8 + j) * N_];
    }
    bf16x8 xh, xl;
#pragma unroll
    for (int j = 0; j < 8; ++j) {
      const short h = (short)(__float_as_uint(xcur[j]) >> 16);  // trunc hi
      xh[j] = h;
      xl[j] = f2bf_r(xcur[j] - bf2f(h));
    }
#pragma unroll
    for (int ot = 0; ot < 4; ++ot) {  // K/Q: B-operand = Wt rows 0..63
      const int off = (ot * 16 + col) * C_ + c0 + quad * 8;
      const bf16x8 bh = *(const bf16x8*)(WtHi + off);
      const bf16x8 bl = *(const bf16x8*)(WtLo + off);
      acc[ot] = __builtin_amdgcn_mfma_f32_16x16x32_bf16(xh, bh, acc[ot], 0, 0, 0);
      acc[ot] = __builtin_amdgcn_mfma_f32_16x16x32_bf16(xl, bh, acc[ot], 0, 0, 0);
      acc[ot] = __builtin_amdgcn_mfma_f32_16x16x32_bf16(xh, bl, acc[ot], 0, 0, 0);
    }
#pragma unroll
    for (int ct = 0; ct < 2; ++ct) {  // V: A-operand = Wt rows 64..95
      const int off = ((64 + ct * 16) + col) * C_ + c0 + quad * 8;
      const bf16x8 ah = *(const bf16x8*)(WtHi + off);
      const bf16x8 al = *(const bf16x8*)(WtLo + off);
      acc[4 + ct] = __builtin_amdgcn_mfma_f32_16x16x32_bf16(ah, xh, acc[4 + ct], 0, 0, 0);
      acc[4 + ct] = __builtin_amdgcn_mfma_f32_16x16x32_bf16(ah, xl, acc[4 + ct], 0, 0, 0);
      acc[4 + ct] = __builtin_amdgcn_mfma_f32_16x16x32_bf16(al, xh, acc[4 + ct], 0, 0, 0);
    }
#pragma unroll
    for (int j = 0; j < 8; ++j) xcur[j] = xnxt[j];
  }

  // K epilogue (ot 0..1): D row=(quad*4+r)+n0 = key i, col-dim = c
#pragma unroll
  for (int ot = 0; ot < 2; ++ot)
#pragma unroll
    for (int r = 0; r < 4; ++r) {
      const int i = n0 + quad * 4 + r;
      const int c = ot * 16 + col;
      const int ln = (i & 31) | (((c >> 3) & 1) << 5);
      Kf[(((size_t)(b * 128 + (i >> 5)) * 2 + (c >> 4)) * 64 + ln) * 8 + (c & 7)] =
          f2bf(acc[ot][r]);
    }
  // Q epilogue (ot 2..3): col j = n, c = o-32
#pragma unroll
  for (int ot = 2; ot < 4; ++ot)
#pragma unroll
    for (int r = 0; r < 4; ++r) {
      const int j = n0 + quad * 4 + r;
      const int c = (ot - 2) * 16 + col;
      const int ln = (j & 31) | (((c >> 3) & 1) << 5);
      Qf[(((size_t)(b * 128 + (j >> 5)) * 2 + (c >> 4)) * 64 + ln) * 8 + (c & 7)] =
          f2bf(acc[ot][r]);
    }
  // V epilogue: c = ct*16+quad*4+r, key n = n0+col
#pragma unroll
  for (int ct = 0; ct < 2; ++ct)
#pragma unroll
    for (int r = 0; r < 4; ++r) {
      const int c = ct * 16 + quad * 4 + r;
      const int n = n0 + col;
      const int ln = c | (((n >> 3) & 1) << 5);
      Vf[((size_t)(b * 256 + (n >> 4)) * 64 + ln) * 8 + (n & 7)] =
          f2bf(acc[4 + ct][r]);
    }
}

// ---------------------------------------------------------------------------
// Kernel 2: 32x32-MFMA flash attention, zero LDS, fragment-major inputs,
// TWO j-tiles per wave x one KV-quarter.  Linear grid 2048 blocks with
// XCD-locality decode: xcd = bid&7 (round-robin dispatch assumption --
// perf heuristic only, correctness-independent), all 64 j-blocks of one
// (b,hq) land on one XCD (4 groups/XCD -> per-XCD K/V working set 512KB
// << 4MB L2, no thrash).  2-deep register prefetch (t unrolled by 2,
// static names) covers L3 latency stragglers.  ~150 unified regs, 2-wave
// class, no spill possible.
// Tripwire: WRITE_SIZE must stay ~8.7 MB (OPart+LPart); growth = spill.
// Last-iter prefetch overreads <=4KB into the adjacent ws buffer: harmless.
// ---------------------------------------------------------------------------
__global__ __launch_bounds__(64, 2) void flash_attn(const short* __restrict__ Kf,
                                                    const short* __restrict__ Qf,
                                                    const short* __restrict__ Vf,
                                                    short* __restrict__ OPart,
                                                    float* __restrict__ LPart) {
  const int bid = blockIdx.x;
  const int xcd = bid & 7, w = bid >> 3;
  const int g = xcd * 4 + (w >> 6);  // (b,hq) group 0..31, XCD-contiguous
  const int b = g >> 2, hq = g & 3;
  const int jb = w & 63;             // 64-col j-block = 2 j-tiles
  const int lane = threadIdx.x;
  const int j32 = lane & 31, h32 = lane >> 5;

  const f32x16 z16 = {0.f};
  // Q B-frags for both j-tiles, loop-invariant, coalesced
  const short* pQ = Qf + ((size_t)(b * 128 + jb * 2) * 2) * 512 + lane * 8;
  bf16x8 qf[2][2];
  qf[0][0] = *(const bf16x8*)(pQ);
  qf[0][1] = *(const bf16x8*)(pQ + 512);
  qf[1][0] = *(const bf16x8*)(pQ + 1024);
  qf[1][1] = *(const bf16x8*)(pQ + 1536);

  const short* pK = Kf + ((size_t)(b * 128 + hq * 32) * 2) * 512 + lane * 8;
  const short* pV = Vf + ((size_t)(b * 256 + hq * 64)) * 512 + lane * 8;

  f32x16 acc[2] = {z16, z16};
  float ps[2] = {0.f, 0.f};

  // 2-deep pipeline: tiles t (set0) and t+1 (set1) in registers
  bf16x8 ka0 = *(const bf16x8*)(pK);
  bf16x8 kb0 = *(const bf16x8*)(pK + 512);
  bf16x8 va0 = *(const bf16x8*)(pV);
  bf16x8 vb0 = *(const bf16x8*)(pV + 512);
  bf16x8 ka1 = *(const bf16x8*)(pK + 1024);
  bf16x8 kb1 = *(const bf16x8*)(pK + 1536);
  bf16x8 va1 = *(const bf16x8*)(pV + 1024);
  bf16x8 vb1 = *(const bf16x8*)(pV + 1536);

  // one 32-key tile: S = K^T Q (2 MFMA), p = exp2(s), pack+permlane32_swap
  // to PV B-frags, O += V @ P (2 MFMA)
  auto tile_step = [&](const bf16x8& ka, const bf16x8& kb,
                       const bf16x8& va, const bf16x8& vb) {
#pragma unroll
    for (int jt = 0; jt < 2; ++jt) {
      __builtin_amdgcn_s_setprio(1);
      f32x16 s = __builtin_amdgcn_mfma_f32_32x32x16_bf16(ka, qf[jt][0], z16, 0, 0, 0);
      s = __builtin_amdgcn_mfma_f32_32x32x16_bf16(kb, qf[jt][1], s, 0, 0, 0);
      __builtin_amdgcn_s_setprio(0);
      float p[16];
#pragma unroll
      for (int r = 0; r < 16; ++r) p[r] = __builtin_amdgcn_exp2f(s[r]);
      ps[jt] += (((p[0] + p[1]) + (p[2] + p[3])) + ((p[4] + p[5]) + (p[6] + p[7]))) +
                (((p[8] + p[9]) + (p[10] + p[11])) + ((p[12] + p[13]) + (p[14] + p[15])));
      unsigned d[8];
#pragma unroll
      for (int k = 0; k < 8; ++k) {
        const unsigned u0 = __float_as_uint(p[2 * k]) + 0x8000u;
        const unsigned u1 = __float_as_uint(p[2 * k + 1]) + 0x8000u;
        d[k] = __builtin_amdgcn_perm(u1, u0, 0x07060302u);  // bf16 pair
      }
      union { unsigned u[4]; bf16x8 v; } f0, f1;
#ifdef HAVE_PLSWAP
      {
        const uint32x2 r0 = __builtin_amdgcn_permlane32_swap(d[0], d[2], false, false);
        f0.u[0] = r0[0]; f0.u[2] = r0[1];
        const uint32x2 r1 = __builtin_amdgcn_permlane32_swap(d[1], d[3], false, false);
        f0.u[1] = r1[0]; f0.u[3] = r1[1];
        const uint32x2 r2 = __builtin_amdgcn_permlane32_swap(d[4], d[6], false, false);
        f1.u[0] = r2[0]; f1.u[2] = r2[1];
        const uint32x2 r3 = __builtin_amdgcn_permlane32_swap(d[5], d[7], false, false);
        f1.u[1] = r3[0]; f1.u[3] = r3[1];
      }
#else
      {
        unsigned xw[8];
#pragma unroll
        for (int k = 0; k < 8; ++k) xw[k] = __shfl_xor((int)d[k], 32);
        f0.u[0] = h32 ? xw[2] : d[0];
        f0.u[1] = h32 ? xw[3] : d[1];
        f0.u[2] = h32 ? d[2] : xw[0];
        f0.u[3] = h32 ? d[3] : xw[1];
        f1.u[0] = h32 ? xw[6] : d[4];
        f1.u[1] = h32 ? xw[7] : d[5];
        f1.u[2] = h32 ? d[6] : xw[4];
        f1.u[3] = h32 ? d[7] : xw[5];
      }
#endif
      __builtin_amdgcn_s_setprio(1);
      acc[jt] = __builtin_amdgcn_mfma_f32_32x32x16_bf16(va, f0.v, acc[jt], 0, 0, 0);
      acc[jt] = __builtin_amdgcn_mfma_f32_32x32x16_bf16(vb, f1.v, acc[jt], 0, 0, 0);
      __builtin_amdgcn_s_setprio(0);
    }
  };

#pragma unroll 1
  for (int t = 0; t < 32; t += 2) {
    // issue tile t+2 loads, compute tile t
    const bf16x8 ka2 = *(const bf16x8*)(pK + 2048);
    const bf16x8 kb2 = *(const bf16x8*)(pK + 2560);
    const bf16x8 va2 = *(const bf16x8*)(pV + 2048);
    const bf16x8 vb2 = *(const bf16x8*)(pV + 2560);
    tile_step(ka0, kb0, va0, vb0);
    // issue tile t+3 loads, compute tile t+1
    const bf16x8 ka3 = *(const bf16x8*)(pK + 3072);
    const bf16x8 kb3 = *(const bf16x8*)(pK + 3584);
    const bf16x8 va3 = *(const bf16x8*)(pV + 3072);
    const bf16x8 vb3 = *(const bf16x8*)(pV + 3584);
    tile_step(ka1, kb1, va1, vb1);
    ka0 = ka2; kb0 = kb2; va0 = va2; vb0 = vb2;
    ka1 = ka3; kb1 = kb3; va1 = va3; vb1 = vb3;
    pK += 2048;
    pV += 2048;
  }

  // ---- epilogue: finish l across halves, write O/l partials ----
  const size_t base = ((size_t)b * NH_ + hq) * N_;
#pragma unroll
  for (int jt = 0; jt < 2; ++jt) {
    const float l = ps[jt] + __shfl_xor(ps[jt], 32);
    const int jg = (jb * 2 + jt) * 32 + j32;
    if (h32 == 0) LPart[base + jg] = l;
    short* OP = OPart + (base + jg) * 32;
#pragma unroll
    for (int g2 = 0; g2 < 4; ++g2) {  // regs 4g..4g+3 -> c = 8g + 4*h32 + 0..3
      bf16x4 o = {f2bf(acc[jt][4 * g2 + 0]), f2bf(acc[jt][4 * g2 + 1]),
                  f2bf(acc[jt][4 * g2 + 2]), f2bf(acc[jt][4 * g2 + 3])};
      *(bf16x4*)(OP + 8 * g2 + 4 * h32) = o;
    }
  }
}

// ---------------------------------------------------------------------------
// Kernel 3: merge 4 KV-quarter partials, normalize, out-proj, residual.
// Grid (64 n-blocks, 2 co-halves, 8 b) = 1024 blocks.
// out[b,co,n] = WoB @ (sum_h O_h / sum_h l_h) + x
// ---------------------------------------------------------------------------
__global__ __launch_bounds__(256) void out_proj(const short* __restrict__ OPart,
                                                const float* __restrict__ LPart,
                                                const short* __restrict__ WoB,
                                                const float* __restrict__ x,
                                                float* __restrict__ out) {
  const int b = blockIdx.z, chalf = blockIdx.y;
  const int tid = threadIdx.x;
  const int wave = tid >> 6, lane = tid & 63;
  const int col = lane & 15, quad = lane >> 4;
  const int jg = blockIdx.x * 64 + wave * 16 + col;  // global n/j
  const int n0 = blockIdx.x * 64 + wave * 16;

  float osum[8];
#pragma unroll
  for (int e = 0; e < 8; ++e) osum[e] = 0.f;
  float lsum = 0.f;
#pragma unroll
  for (int h = 0; h < NH_; ++h) {
    const size_t p = ((size_t)b * NH_ + h) * N_ + jg;
    const bf16x8 o = *(const bf16x8*)(OPart + p * 32 + quad * 8);
#pragma unroll
    for (int e = 0; e < 8; ++e) osum[e] += bf2f(o[e]);
    lsum += LPart[p];
  }
  const float linv = 1.f / lsum;
  bf16x8 bf;
#pragma unroll
  for (int e = 0; e < 8; ++e) bf[e] = f2bf(osum[e] * linv);

  const f32x4 z4 = {0.f, 0.f, 0.f, 0.f};
  const float* xb = x + (size_t)b * C_ * N_;
  float* ob = out + (size_t)b * C_ * N_;
#pragma unroll
  for (int ct = 0; ct < 8; ++ct) {
    const int ctg = chalf * 8 + ct;
    const bf16x8 af = *(const bf16x8*)(WoB + (ctg * 16 + col) * 32 + quad * 8);
    const f32x4 a = __builtin_amdgcn_mfma_f32_16x16x32_bf16(af, bf, z4, 0, 0, 0);
#pragma unroll
    for (int r = 0; r < 4; ++r) {
      const size_t idx = (size_t)(ctg * 16 + quad * 4 + r) * N_ + n0 + col;
      ob[idx] = a[r] + xb[idx];
    }
  }
}

// ---------------------------------------------------------------------------
extern "C" void kernel_launch(void* const* d_in, const int* in_sizes, int n_in,
                              void* d_out, int out_size, void* d_ws,
                              size_t ws_size, hipStream_t stream) {
  const float* x = (const float*)d_in[0];      // [8,256,64,64]
  const float* Wt = (const float*)d_in[1];     // [96,256]
  const float* Wo = (const float*)d_in[2];     // [256,32]
  const float* scale = (const float*)d_in[3];  // [1]
  float* out = (float*)d_out;

  // ws: OPart bf16 [8][4][4096][32] (8.4 MB) | LPart f32 [8][4][4096] (0.5 MB)
  //   | Kf (2 MB) | Qf (2 MB) | Vf (2 MB) | WtHi | WtLo | WoB  (~15 MB)
  short* OPart = (short*)d_ws;
  float* LPart = (float*)(OPart + (size_t)B_ * NH_ * N_ * 32);
  short* Kf = (short*)(LPart + (size_t)B_ * NH_ * N_);
  short* Qf = Kf + (size_t)B_ * 128 * 1024;
  short* Vf = Qf + (size_t)B_ * 128 * 1024;
  short* WtHi = Vf + (size_t)B_ * 256 * 512;
  short* WtLo = WtHi + 96 * C_;
  short* WoB = WtLo + 96 * C_;

  prep_weights<<<dim3(128), 256, 0, stream>>>(Wt, Wo, scale, WtHi, WtLo, WoB);
  qkv_mfma<<<dim3(64, B_), 256, 0, stream>>>(x, WtHi, WtLo, Kf, Qf, Vf);
  flash_attn<<<dim3(2048), 64, 0, stream>>>(Kf, Qf, Vf, OPart, LPart);
  out_proj<<<dim3(64, 2, B_), 256, 0, stream>>>(OPart, LPart, WoB, x, out);
}